// Round 4
// baseline (36.892 us; speedup 1.0000x reference)
//
#include <hip/hip_runtime.h>

#define D_  128
#define K2_ 256
#define BM  16

typedef short bf16x8 __attribute__((ext_vector_type(8)));
typedef float f32x4  __attribute__((ext_vector_type(4)));

__device__ __forceinline__ unsigned short f2bf(float f) {
  unsigned int u = __float_as_uint(f);
  u += 0x7fffu + ((u >> 16) & 1u);       // round-to-nearest-even
  return (unsigned short)(u >> 16);
}
__device__ __forceinline__ float bf2f(unsigned short s) {
  return __uint_as_float(((unsigned int)s) << 16);
}

// 8 consecutive f32 -> bf16x8 (hi only)
__device__ __forceinline__ bf16x8 cvt8(const float* p) {
  float4 a = *(const float4*)p, b = *(const float4*)(p + 4);
  bf16x8 r;
  r[0]=(short)f2bf(a.x); r[1]=(short)f2bf(a.y); r[2]=(short)f2bf(a.z); r[3]=(short)f2bf(a.w);
  r[4]=(short)f2bf(b.x); r[5]=(short)f2bf(b.y); r[6]=(short)f2bf(b.z); r[7]=(short)f2bf(b.w);
  return r;
}
// 8 consecutive f32 -> bf16 hi + bf16 lo residual
__device__ __forceinline__ void split8(const float* p, bf16x8* hi, bf16x8* lo) {
  float4 a = *(const float4*)p, b = *(const float4*)(p + 4);
  const float f[8] = {a.x, a.y, a.z, a.w, b.x, b.y, b.z, b.w};
  #pragma unroll
  for (int e = 0; e < 8; ++e) {
    unsigned short h = f2bf(f[e]);
    (*hi)[e] = (short)h;
    (*lo)[e] = (short)f2bf(f[e] - bf2f(h));
  }
}
// 8 stride-separated f32 -> bf16x8 (hi only)
__device__ __forceinline__ bf16x8 cvt8s(const float* p, int stride) {
  bf16x8 r;
  #pragma unroll
  for (int e = 0; e < 8; ++e) r[e] = (short)f2bf(p[e * stride]);
  return r;
}

__global__ __launch_bounds__(256) void fused_jvp_kernel(
    const float* __restrict__ input_,
    const float* __restrict__ W1, const float* __restrict__ b1,
    const float* __restrict__ W2, const float* __restrict__ b2,
    float* __restrict__ out)
{
  // LDS: hb (h, dead after P2 K-loop; ub does NOT alias it to avoid an extra
  // barrier... actually ub gets its own 4KB), m2b (dead after P2 K-loop,
  // aliased by rb whose first write is after the P2->P3 barrier: safe).
  __shared__ __align__(16) unsigned short hb [BM * K2_];   // 8 KB
  __shared__ __align__(16) unsigned short m2b[BM * K2_];   // 8 KB
  __shared__ __align__(16) unsigned short ub [BM * D_];    // 4 KB
  unsigned short* rb = m2b;                                // alias (safe: barrier between)

  const int tid  = threadIdx.x;
  const int lane = tid & 63;
  const int wv   = tid >> 6;        // wave 0..3
  const int l15  = lane & 15;
  const int lg   = lane >> 4;       // 0..3
  const long rowbase = (long)blockIdx.x * BM;
  const float* arow = input_ + (rowbase + l15) * 256;   // this lane's A-row

  // swizzled LDS A-fragment read (lane=row, 8 contiguous k)
  auto ldsA = [&](const unsigned short* tile, int S, int kbase) -> bf16x8 {
    int idx = (l15 * S + kbase + lg * 8) ^ ((l15 & 7) << 3);
    return *(const bf16x8*)(&tile[idx]);
  };

  // ---- P1: z1 = x*W1^T + b1 (3-term split) ; w = v*W1^T   (out 16x256)
  f32x4 accz[4] = {};
  f32x4 accw[4] = {};
  #pragma unroll
  for (int k32 = 0; k32 < 4; ++k32) {
    const int ko = k32 * 32 + lg * 8;
    bf16x8 axh, axl;
    split8(arow + ko, &axh, &axl);
    bf16x8 av = cvt8(arow + 128 + ko);
    #pragma unroll
    for (int nt = 0; nt < 4; ++nt) {
      const int cg = wv * 64 + nt * 16 + l15;
      bf16x8 bh, bl;
      split8(W1 + cg * 128 + ko, &bh, &bl);
      accz[nt] = __builtin_amdgcn_mfma_f32_16x16x32_bf16(axh, bh, accz[nt], 0, 0, 0);
      accz[nt] = __builtin_amdgcn_mfma_f32_16x16x32_bf16(axh, bl, accz[nt], 0, 0, 0);
      accz[nt] = __builtin_amdgcn_mfma_f32_16x16x32_bf16(axl, bh, accz[nt], 0, 0, 0);
      accw[nt] = __builtin_amdgcn_mfma_f32_16x16x32_bf16(av,  bh, accw[nt], 0, 0, 0);
    }
  }
  unsigned int maskbits = 0;        // ReLU mask, reused in P3 epilogue (same lane map)
  #pragma unroll
  for (int nt = 0; nt < 4; ++nt) {
    int cg = wv * 64 + nt * 16 + l15;
    float bias = b1[cg];
    #pragma unroll
    for (int q = 0; q < 4; ++q) {
      int rg = lg * 4 + q;
      float z = accz[nt][q] + bias;
      if (__builtin_expect(fabsf(z) < 1e-4f, 0)) {
        // borderline ReLU: recompute exactly in f64 (rare: ~1e-4 of elements)
        const float* xr  = input_ + (rowbase + rg) * 256;
        const float* w1r = W1 + (size_t)cg * D_;
        double zd = (double)bias;
        for (int k = 0; k < D_; ++k) zd += (double)xr[k] * (double)w1r[k];
        z = (float)zd;
      }
      maskbits |= (z > 0.f ? 1u : 0u) << (nt * 4 + q);
      float hv = z > 0.f ? z : 0.f;
      float mw = z > 0.f ? accw[nt][q] : 0.f;
      int idx = (rg * K2_ + cg) ^ ((rg & 7) << 3);
      hb[idx]  = f2bf(hv);
      m2b[idx] = f2bf(mw);
    }
  }
  __syncthreads();

  // ---- P2: sdot = h*W2^T ; y = m2*W2^T  (out 16x128, wave owns 32 cols)
  f32x4 accs[2] = {};
  f32x4 accy[2] = {};
  #pragma unroll
  for (int k32 = 0; k32 < 8; ++k32) {
    const int ko = k32 * 32 + lg * 8;
    bf16x8 ah = ldsA(hb,  K2_, k32 * 32);
    bf16x8 am = ldsA(m2b, K2_, k32 * 32);
    #pragma unroll
    for (int nt = 0; nt < 2; ++nt) {
      int cg2 = wv * 32 + nt * 16 + l15;
      bf16x8 bw = cvt8(W2 + cg2 * 256 + ko);
      accs[nt] = __builtin_amdgcn_mfma_f32_16x16x32_bf16(ah, bw, accs[nt], 0, 0, 0);
      accy[nt] = __builtin_amdgcn_mfma_f32_16x16x32_bf16(am, bw, accy[nt], 0, 0, 0);
    }
  }
  float coefr[2][4], ginvr[2][4], vreg[2][4];
  #pragma unroll
  for (int nt = 0; nt < 2; ++nt) {
    int cg2 = wv * 32 + nt * 16 + l15;
    float bias = b2[cg2];
    float sgn  = (cg2 < 4) ? -1.f : 1.f;
    #pragma unroll
    for (int q = 0; q < 4; ++q) {
      int rg = lg * 4 + q;
      float sv = 1.f / (1.f + __expf(-(accs[nt][q] + bias)));
      float cf = sgn * sv * (1.f - sv);
      float gi = 1.f / ((sv + 0.618f) * sgn);
      coefr[nt][q] = cf;
      ginvr[nt][q] = gi;
      float vvf = input_[(rowbase + rg) * 256 + 128 + cg2];   // exact f32 v
      vreg[nt][q] = vvf;
      out[(rowbase + rg) * 256 + cg2] = vvf;                  // out[:, :128] = v
      int idxd = (rg * D_ + cg2) ^ ((rg & 7) << 3);
      ub[idxd] = f2bf(vvf * vvf * cf);                        // u = v^2 * coef
    }
  }
  __syncthreads();

  // ---- P3: p = u*W2  (out 16x256) ; r = mask .* p (mask from registers)
  f32x4 accp[4] = {};
  #pragma unroll
  for (int k32 = 0; k32 < 4; ++k32) {
    bf16x8 au = ldsA(ub, D_, k32 * 32);
    #pragma unroll
    for (int nt = 0; nt < 4; ++nt) {
      int cg = wv * 64 + nt * 16 + l15;
      bf16x8 bw = cvt8s(W2 + (k32 * 32 + lg * 8) * 256 + cg, 256);
      accp[nt] = __builtin_amdgcn_mfma_f32_16x16x32_bf16(au, bw, accp[nt], 0, 0, 0);
    }
  }
  #pragma unroll
  for (int nt = 0; nt < 4; ++nt) {
    int cg = wv * 64 + nt * 16 + l15;
    #pragma unroll
    for (int q = 0; q < 4; ++q) {
      int rg = lg * 4 + q;
      int idx = (rg * K2_ + cg) ^ ((rg & 7) << 3);
      rb[idx] = ((maskbits >> (nt * 4 + q)) & 1u) ? f2bf(accp[nt][q]) : (unsigned short)0;
    }
  }
  __syncthreads();

  // ---- P4: t1pre = r*W1  (out 16x128) ; final epilogue from registers
  f32x4 acct[2] = {};
  #pragma unroll
  for (int k32 = 0; k32 < 8; ++k32) {
    bf16x8 ar = ldsA(rb, K2_, k32 * 32);
    #pragma unroll
    for (int nt = 0; nt < 2; ++nt) {
      int cg2 = wv * 32 + nt * 16 + l15;
      bf16x8 bw = cvt8s(W1 + (k32 * 32 + lg * 8) * 128 + cg2, 128);
      acct[nt] = __builtin_amdgcn_mfma_f32_16x16x32_bf16(ar, bw, acct[nt], 0, 0, 0);
    }
  }
  #pragma unroll
  for (int nt = 0; nt < 2; ++nt) {
    int cg2 = wv * 32 + nt * 16 + l15;
    #pragma unroll
    for (int q = 0; q < 4; ++q) {
      int rg = lg * 4 + q;
      float gi = ginvr[nt][q];
      float dv = -gi * acct[nt][q]
               + 2.f * vreg[nt][q] * gi * coefr[nt][q] * accy[nt][q];
      out[(rowbase + rg) * 256 + 128 + cg2] = dv;
    }
  }
}

extern "C" void kernel_launch(void* const* d_in, const int* in_sizes, int n_in,
                              void* d_out, int out_size, void* d_ws, size_t ws_size,
                              hipStream_t stream) {
  const float* input_ = (const float*)d_in[1];
  const float* W1     = (const float*)d_in[2];
  const float* b1     = (const float*)d_in[3];
  const float* W2     = (const float*)d_in[4];
  const float* b2     = (const float*)d_in[5];
  float* out = (float*)d_out;
  int N = in_sizes[1] / (2 * D_);
  fused_jvp_kernel<<<dim3(N / BM), dim3(256), 0, stream>>>(input_, W1, b1, W2, b2, out);
}